// Round 3
// baseline (3320.635 us; speedup 1.0000x reference)
//
#include <hip/hip_runtime.h>
#include <math.h>

#define BB 256
#define SS 2048
#define EE 64
#define HH 128
#define MB 16              // batches per block
#define NB (BB / MB)       // grid = 16 blocks
#define LROW 136           // padded f16 row length (272 B): 2-way-max bank aliasing

typedef _Float16 f16x8 __attribute__((ext_vector_type(8)));
typedef _Float16 half2_t __attribute__((ext_vector_type(2)));
typedef float f32x4 __attribute__((ext_vector_type(4)));

#if defined(__has_builtin)
#if __has_builtin(__builtin_amdgcn_exp2f)
#define EXP2F(x) __builtin_amdgcn_exp2f(x)
#else
#define EXP2F(x) exp2f(x)
#endif
#if __has_builtin(__builtin_amdgcn_rcpf)
#define RCPF(x) __builtin_amdgcn_rcpf(x)
#else
#define RCPF(x) (1.0f / (x))
#endif
#else
#define EXP2F(x) exp2f(x)
#define RCPF(x) (1.0f / (x))
#endif

__device__ __forceinline__ float sigm_f(float x) {
    float e = EXP2F(-1.442695041f * x);
    return RCPF(1.0f + e);
}
__device__ __forceinline__ float tanh_f(float x) {
    float e = EXP2F(2.885390082f * x);
    return 1.0f - 2.0f * RCPF(1.0f + e);
}

__device__ __forceinline__ f32x4 mfma16(f16x8 a, f16x8 b, f32x4 c) {
    return __builtin_amdgcn_mfma_f32_16x16x32_f16(a, b, c, 0, 0, 0);
}

__device__ __forceinline__ f16x8 pack8(float4 a, float4 b) {
    f16x8 r;
    r[0] = (_Float16)a.x; r[1] = (_Float16)a.y;
    r[2] = (_Float16)a.z; r[3] = (_Float16)a.w;
    r[4] = (_Float16)b.x; r[5] = (_Float16)b.y;
    r[6] = (_Float16)b.z; r[7] = (_Float16)b.w;
    return r;
}

// Grid = 16 blocks x 512 threads; block handles batches [16*blk, 16*blk+16).
// Wave w (0..7) owns unit tile [16w, 16w+16).
// Per step, per wave: 28 v_mfma_f32_16x16x32_f16:
//   gates (4 tiles x K=128/32=4) = 16, x-proj (4 tiles x K=64/32=2) = 8,
//   W_d (1 tile x 4) = 4.
// MFMA C layout: col(unit) = lane&15, rows(batch) = (lane>>4)*4 + i.
// -> f,i,o,ct,cdot for one (batch,unit) are all in ONE lane: activations are
// lane-local, no cross-lane reduction at all. f32 c-state stays in registers
// (same lane owns the same (batch,unit) every step).
// A operands (h, c, x as f16) live in LDS rows padded to 272 B (<=2-way banks).
__global__ __launch_bounds__(512, 2) void tlstm_mfma_kernel(
    const float* __restrict__ inputs,        // [B,S,E]
    const float* __restrict__ time_interval, // [B,S]
    const float* __restrict__ W_all,         // [4H,H]
    const float* __restrict__ b_all,         // [4H]
    const float* __restrict__ U_all,         // [4H,E]
    const float* __restrict__ b_u,           // [4H]
    const float* __restrict__ W_d,           // [H,H]
    const float* __restrict__ b_d,           // [H]
    const float* __restrict__ W_out,         // [1,H]
    const float* __restrict__ b_out,         // [1]
    float* __restrict__ out)                 // [B]
{
    const int t    = threadIdx.x;
    const int l    = t & 63;
    const int w    = t >> 6;         // wave 0..7
    const int n16  = l & 15;         // C/B col within tile
    const int g4   = l >> 4;         // lane quarter 0..3
    const int unit = w * 16 + n16;   // this lane's unit (C col)
    const int b0   = blockIdx.x * MB;

    __shared__ __align__(16) _Float16 sh_h[2][MB * LROW];
    __shared__ __align__(16) _Float16 sh_c[2][MB * LROW];
    __shared__ __align__(16) _Float16 sh_x[2][MB * LROW];  // cols 0..63 used
    __shared__ __align__(16) float sh_dt[2][MB];
    __shared__ float sh_red[MB][HH];
    __shared__ float sh_r2[MB][8];

    // ---- loop-invariant weights as B-fragments (f16) ----
    // B-frag layout: col = lane&15 (row of W, i.e. the gate/unit), k = (lane>>4)*8 + j.
    f16x8 wB[4][4];   // [gate q][K-subtile]
    f16x8 uB[4][2];
    f16x8 dB[4];
    float bq[4];
    #pragma unroll
    for (int q = 0; q < 4; ++q) {
        const int row = q * HH + unit;           // W row = gate
        const float* wp = W_all + (size_t)row * HH + g4 * 8;
        #pragma unroll
        for (int kk = 0; kk < 4; ++kk) {
            const float4* p = (const float4*)(wp + kk * 32);
            wB[q][kk] = pack8(p[0], p[1]);
        }
        const float* up = U_all + (size_t)row * EE + g4 * 8;
        #pragma unroll
        for (int kk = 0; kk < 2; ++kk) {
            const float4* p = (const float4*)(up + kk * 32);
            uB[q][kk] = pack8(p[0], p[1]);
        }
        bq[q] = b_all[row] + b_u[row];
    }
    {
        const float* dp = W_d + (size_t)unit * HH + g4 * 8;
        #pragma unroll
        for (int kk = 0; kk < 4; ++kk) {
            const float4* p = (const float4*)(dp + kk * 32);
            dB[kk] = pack8(p[0], p[1]);
        }
    }
    const float bd_r   = b_d[unit];
    const float wout_r = W_out[unit];

    // ---- x/dt staging assignment (coalesced: 32 lanes x float2 per batch row) ----
    const int sb  = t >> 5;            // staging batch 0..15
    const int se  = (t & 31) * 2;      // staging elem pair
    const float* xgb = inputs + ((size_t)(b0 + sb) * SS) * EE + se;
    const int sxw = sb * LROW + se;
    const float* dtp = time_interval + (size_t)(b0 + (t < MB ? t : 0)) * SS;

    // ---- A-fragment index: row(batch) = lane&15, k = (lane>>4)*8 (+kk*32) ----
    const int aoff = (l & 15) * LROW + g4 * 8;
    // ---- C-write index: batch rows (lane>>4)*4 + i, col = unit ----
    const int woff = (g4 * 4) * LROW + unit;

    // ---- prologue: zero h/c buf0, stage x[0]/dt[0] ----
    for (int i = t; i < MB * LROW; i += 512) {
        sh_h[0][i] = (_Float16)0.f;
        sh_c[0][i] = (_Float16)0.f;
    }
    {
        float2 x0 = *(const float2*)(xgb);
        half2_t xp; xp.x = (_Float16)x0.x; xp.y = (_Float16)x0.y;
        *(half2_t*)&sh_x[0][sxw] = xp;
        if (t < MB) sh_dt[0][t] = dtp[0];
    }
    float cst[4]  = {0.f, 0.f, 0.f, 0.f};   // f32 cell state (4 batches x my unit)
    float hsum[4] = {0.f, 0.f, 0.f, 0.f};
    __syncthreads();

#define TLSTM_STEP(s, CUR, NXT)                                               \
    {                                                                         \
        const int sn = ((s) + 1 < SS) ? (s) + 1 : SS - 1;                     \
        float2 xr = *(const float2*)(xgb + (size_t)sn * EE);                  \
        float dtr = 0.f;                                                      \
        if (t < MB) dtr = dtp[sn];                                            \
        const float4 dtv = *(const float4*)&sh_dt[CUR][g4 * 4];               \
        f32x4 a0 = {bq[0], bq[0], bq[0], bq[0]};                              \
        f32x4 a1 = {bq[1], bq[1], bq[1], bq[1]};                              \
        f32x4 a2 = {bq[2], bq[2], bq[2], bq[2]};                              \
        f32x4 a3 = {bq[3], bq[3], bq[3], bq[3]};                              \
        f32x4 adw = {bd_r, bd_r, bd_r, bd_r};                                 \
        _Pragma("unroll")                                                     \
        for (int kk = 0; kk < 4; ++kk) {                                      \
            f16x8 ah = *(const f16x8*)&sh_h[CUR][aoff + kk * 32];             \
            a0 = mfma16(ah, wB[0][kk], a0);                                   \
            a1 = mfma16(ah, wB[1][kk], a1);                                   \
            a2 = mfma16(ah, wB[2][kk], a2);                                   \
            a3 = mfma16(ah, wB[3][kk], a3);                                   \
            f16x8 ac = *(const f16x8*)&sh_c[CUR][aoff + kk * 32];             \
            adw = mfma16(ac, dB[kk], adw);                                    \
        }                                                                     \
        _Pragma("unroll")                                                     \
        for (int kk = 0; kk < 2; ++kk) {                                      \
            f16x8 ax = *(const f16x8*)&sh_x[CUR][aoff + kk * 32];             \
            a0 = mfma16(ax, uB[0][kk], a0);                                   \
            a1 = mfma16(ax, uB[1][kk], a1);                                   \
            a2 = mfma16(ax, uB[2][kk], a2);                                   \
            a3 = mfma16(ax, uB[3][kk], a3);                                   \
        }                                                                     \
        _Pragma("unroll")                                                     \
        for (int i = 0; i < 4; ++i) {                                         \
            float cdot = tanh_f(adw[i]);                                      \
            float cadj = __builtin_fmaf(cdot, dtv[i] - 1.0f, cst[i]);         \
            float fg = sigm_f(a0[i]);                                         \
            float ig = sigm_f(a1[i]);                                         \
            float og = sigm_f(a2[i]);                                         \
            float cg = sigm_f(a3[i]);                                         \
            float cn = __builtin_fmaf(fg, cadj, ig * cg);                     \
            float hn = og * tanh_f(cn);                                       \
            cst[i]  = cn;                                                     \
            hsum[i] += hn;                                                    \
            sh_h[NXT][woff + i * LROW] = (_Float16)hn;                        \
            sh_c[NXT][woff + i * LROW] = (_Float16)cn;                        \
        }                                                                     \
        {                                                                     \
            half2_t xp; xp.x = (_Float16)xr.x; xp.y = (_Float16)xr.y;         \
            *(half2_t*)&sh_x[NXT][sxw] = xp;                                  \
        }                                                                     \
        if (t < MB) sh_dt[NXT][t] = dtr;                                      \
        __syncthreads();                                                      \
    }

    for (int s = 0; s < SS; s += 2) {
        TLSTM_STEP(s,     0, 1)
        TLSTM_STEP(s + 1, 1, 0)
    }
#undef TLSTM_STEP

    // ---- epilogue: out[b] = sum_u hsum[b][u]*W_out[u] + S*b_out ----
    #pragma unroll
    for (int i = 0; i < 4; ++i)
        sh_red[g4 * 4 + i][unit] = hsum[i] * wout_r;
    __syncthreads();
    if (t < 128) {
        const int bb = t >> 3, seg = t & 7;
        float acc = 0.f;
        #pragma unroll
        for (int j = 0; j < 16; ++j) acc += sh_red[bb][seg * 16 + j];
        sh_r2[bb][seg] = acc;
    }
    __syncthreads();
    if (t < MB) {
        float acc = 0.f;
        #pragma unroll
        for (int j = 0; j < 8; ++j) acc += sh_r2[t][j];
        out[b0 + t] = acc + (float)SS * b_out[0];
    }
}

extern "C" void kernel_launch(void* const* d_in, const int* in_sizes, int n_in,
                              void* d_out, int out_size, void* d_ws, size_t ws_size,
                              hipStream_t stream) {
    const float* inputs        = (const float*)d_in[0];
    const float* time_interval = (const float*)d_in[1];
    const float* W_all         = (const float*)d_in[2];
    const float* b_all         = (const float*)d_in[3];
    const float* U_all         = (const float*)d_in[4];
    const float* b_u           = (const float*)d_in[5];
    const float* W_d           = (const float*)d_in[6];
    const float* b_d           = (const float*)d_in[7];
    const float* W_out         = (const float*)d_in[8];
    const float* b_out         = (const float*)d_in[9];
    float* out = (float*)d_out;

    tlstm_mfma_kernel<<<dim3(NB), dim3(512), 0, stream>>>(
        inputs, time_interval, W_all, b_all, U_all, b_u,
        W_d, b_d, W_out, b_out, out);
}

// Round 4
// 2686.511 us; speedup vs baseline: 1.2360x; 1.2360x over previous
//
#include <hip/hip_runtime.h>
#include <math.h>

#define BB 256
#define SS 2048
#define EE 64
#define HH 128
#define MB 16              // batches per block
#define NB (BB / MB)       // grid = 16 blocks
#define LROW 136           // padded f16 row length (272 B)

typedef _Float16 f16x8 __attribute__((ext_vector_type(8)));
typedef float f32x4 __attribute__((ext_vector_type(4)));

#if defined(__has_builtin)
#if __has_builtin(__builtin_amdgcn_exp2f)
#define EXP2F(x) __builtin_amdgcn_exp2f(x)
#else
#define EXP2F(x) exp2f(x)
#endif
#if __has_builtin(__builtin_amdgcn_rcpf)
#define RCPF(x) __builtin_amdgcn_rcpf(x)
#else
#define RCPF(x) (1.0f / (x))
#endif
#else
#define EXP2F(x) exp2f(x)
#define RCPF(x) (1.0f / (x))
#endif

__device__ __forceinline__ float sigm_f(float x) {
    float e = EXP2F(-1.442695041f * x);
    return RCPF(1.0f + e);
}
__device__ __forceinline__ float tanh_f(float x) {
    float e = EXP2F(2.885390082f * x);
    return 1.0f - 2.0f * RCPF(1.0f + e);
}

__device__ __forceinline__ f32x4 mfma16(f16x8 a, f16x8 b, f32x4 c) {
    return __builtin_amdgcn_mfma_f32_16x16x32_f16(a, b, c, 0, 0, 0);
}

__device__ __forceinline__ f16x8 pack8(float4 a, float4 b) {
    f16x8 r;
    r[0] = (_Float16)a.x; r[1] = (_Float16)a.y;
    r[2] = (_Float16)a.z; r[3] = (_Float16)a.w;
    r[4] = (_Float16)b.x; r[5] = (_Float16)b.y;
    r[6] = (_Float16)b.z; r[7] = (_Float16)b.w;
    return r;
}

// Grid = 16 blocks x 512 threads; block = batches [16*blk, +16), wave w = units
// [16w, +16). Per step per wave: 8 ds_read_b128 (h:4, c:4) + 28 MFMA + lane-local
// epilogue. x and dt come straight from global into registers (A-frag layout),
// prefetched 2 steps deep (~1.5-step latency cover) -- no LDS staging, no
// per-step HBM stall. h/c f16 copies round-trip through LDS only for the
// cross-wave A-operands; the f32 cell state stays in registers (lane owns the
// same (batch,unit) every step).
__global__ __launch_bounds__(512, 2) void tlstm_mfma2_kernel(
    const float* __restrict__ inputs,        // [B,S,E]
    const float* __restrict__ time_interval, // [B,S]
    const float* __restrict__ W_all,         // [4H,H]
    const float* __restrict__ b_all,         // [4H]
    const float* __restrict__ U_all,         // [4H,E]
    const float* __restrict__ b_u,           // [4H]
    const float* __restrict__ W_d,           // [H,H]
    const float* __restrict__ b_d,           // [H]
    const float* __restrict__ W_out,         // [1,H]
    const float* __restrict__ b_out,         // [1]
    float* __restrict__ out)                 // [B]
{
    const int t    = threadIdx.x;
    const int l    = t & 63;
    const int w    = t >> 6;         // wave 0..7
    const int n16  = l & 15;         // batch row (A) / unit col (B,C)
    const int Q    = l >> 4;         // lane quarter
    const int unit = w * 16 + n16;
    const int b0   = blockIdx.x * MB;

    __shared__ __align__(16) _Float16 sh_h[2][MB * LROW];
    __shared__ __align__(16) _Float16 sh_c[2][MB * LROW];
    __shared__ float sh_red[MB][HH];
    __shared__ float sh_r2[MB][8];

    // ---- loop-invariant weights as B-fragments (f16, registers) ----
    f16x8 wB[4][4];   // [gate][K-subtile]
    f16x8 uB[4][2];
    f16x8 dB[4];
    float bq[4];
    #pragma unroll
    for (int q = 0; q < 4; ++q) {
        const int row = q * HH + unit;
        const float* wp = W_all + (size_t)row * HH + Q * 8;
        #pragma unroll
        for (int kk = 0; kk < 4; ++kk) {
            const float4* p = (const float4*)(wp + kk * 32);
            wB[q][kk] = pack8(p[0], p[1]);
        }
        const float* up = U_all + (size_t)row * EE + Q * 8;
        #pragma unroll
        for (int kk = 0; kk < 2; ++kk) {
            const float4* p = (const float4*)(up + kk * 32);
            uB[q][kk] = pack8(p[0], p[1]);
        }
        bq[q] = b_all[row] + b_u[row];
    }
    {
        const float* dp = W_d + (size_t)unit * HH + Q * 8;
        #pragma unroll
        for (int kk = 0; kk < 4; ++kk) {
            const float4* p = (const float4*)(dp + kk * 32);
            dB[kk] = pack8(p[0], p[1]);
        }
    }
    const float bd_r   = b_d[unit];
    const float wout_r = W_out[unit];

    // ---- per-lane global pointers (x in A-frag order, dt per owned batch) ----
    const float* xgb = inputs + (size_t)(b0 + n16) * SS * EE + Q * 8;
    const float* dr0 = time_interval + (size_t)(b0 + 4 * Q + 0) * SS;
    const float* dr1 = time_interval + (size_t)(b0 + 4 * Q + 1) * SS;
    const float* dr2 = time_interval + (size_t)(b0 + 4 * Q + 2) * SS;
    const float* dr3 = time_interval + (size_t)(b0 + 4 * Q + 3) * SS;

    const int aoff = n16 * LROW + Q * 8;          // A-frag base (h, c)
    const int woff = (Q * 4) * LROW + unit;       // C-write base

    // ---- prologue: zero state buf0, prime x/dt pipelines ----
    for (int i = t; i < MB * LROW; i += 512) {
        sh_h[0][i] = (_Float16)0.f;
        sh_c[0][i] = (_Float16)0.f;
    }
    f16x8 xf0, xf1;               // x[s] as A-frags (kk=0,1)
    {
        const float4* p = (const float4*)(xgb);
        xf0 = pack8(p[0], p[1]);
        const float4* p2 = (const float4*)(xgb + 32);
        xf1 = pack8(p2[0], p2[1]);
    }
    // raw in-flight sets, parity-named: xi{p} filled at step s (parity p) for s+2
    float4 xi0_a = {0,0,0,0}, xi0_b = {0,0,0,0}, xi0_c = {0,0,0,0}, xi0_d = {0,0,0,0};
    float4 xi1_a, xi1_b, xi1_c, xi1_d;
    {
        const float* xp = xgb + EE;               // x[1]
        xi1_a = ((const float4*)xp)[0];
        xi1_b = ((const float4*)(xp + 4))[0];
        xi1_c = ((const float4*)(xp + 32))[0];
        xi1_d = ((const float4*)(xp + 36))[0];
    }
    float dc0 = dr0[0], dc1 = dr1[0], dc2 = dr2[0], dc3 = dr3[0];   // dt[s]
    float di0_0 = 0.f, di0_1 = 0.f, di0_2 = 0.f, di0_3 = 0.f;
    float di1_0 = dr0[1], di1_1 = dr1[1], di1_2 = dr2[1], di1_3 = dr3[1];

    float cst[4]  = {0.f, 0.f, 0.f, 0.f};
    float hsum[4] = {0.f, 0.f, 0.f, 0.f};
    __syncthreads();

#define TLSTM_STEP(s, CUR, NXT)                                               \
    {                                                                         \
        /* issue loads for s+2 (lands in xi/di parity CUR) */                 \
        const int s2 = ((s) + 2 < SS) ? (s) + 2 : SS - 1;                     \
        {                                                                     \
            const float* xp = xgb + (size_t)s2 * EE;                          \
            xi##CUR##_a = ((const float4*)xp)[0];                             \
            xi##CUR##_b = ((const float4*)(xp + 4))[0];                       \
            xi##CUR##_c = ((const float4*)(xp + 32))[0];                      \
            xi##CUR##_d = ((const float4*)(xp + 36))[0];                      \
            di##CUR##_0 = dr0[s2]; di##CUR##_1 = dr1[s2];                     \
            di##CUR##_2 = dr2[s2]; di##CUR##_3 = dr3[s2];                     \
        }                                                                     \
        f32x4 a0  = {bq[0], bq[0], bq[0], bq[0]};                             \
        f32x4 a1  = {bq[1], bq[1], bq[1], bq[1]};                             \
        f32x4 a2  = {bq[2], bq[2], bq[2], bq[2]};                             \
        f32x4 a3  = {bq[3], bq[3], bq[3], bq[3]};                             \
        f32x4 adw = {bd_r, bd_r, bd_r, bd_r};                                 \
        _Pragma("unroll")                                                     \
        for (int kk = 0; kk < 4; ++kk) {                                      \
            f16x8 ah = *(const f16x8*)&sh_h[CUR][aoff + kk * 32];             \
            a0 = mfma16(ah, wB[0][kk], a0);                                   \
            a1 = mfma16(ah, wB[1][kk], a1);                                   \
            a2 = mfma16(ah, wB[2][kk], a2);                                   \
            a3 = mfma16(ah, wB[3][kk], a3);                                   \
            f16x8 ac = *(const f16x8*)&sh_c[CUR][aoff + kk * 32];             \
            adw = mfma16(ac, dB[kk], adw);                                    \
        }                                                                     \
        a0 = mfma16(xf0, uB[0][0], a0);  a0 = mfma16(xf1, uB[0][1], a0);      \
        a1 = mfma16(xf0, uB[1][0], a1);  a1 = mfma16(xf1, uB[1][1], a1);      \
        a2 = mfma16(xf0, uB[2][0], a2);  a2 = mfma16(xf1, uB[2][1], a2);      \
        a3 = mfma16(xf0, uB[3][0], a3);  a3 = mfma16(xf1, uB[3][1], a3);      \
        {                                                                     \
            const float dtv0 = dc0, dtv1 = dc1, dtv2 = dc2, dtv3 = dc3;       \
            _Pragma("unroll")                                                 \
            for (int i = 0; i < 4; ++i) {                                     \
                const float dti = (i == 0) ? dtv0 : (i == 1) ? dtv1           \
                                  : (i == 2) ? dtv2 : dtv3;                   \
                float cdot = tanh_f(adw[i]);                                  \
                float cadj = __builtin_fmaf(cdot, dti - 1.0f, cst[i]);        \
                float fg = sigm_f(a0[i]);                                     \
                float ig = sigm_f(a1[i]);                                     \
                float og = sigm_f(a2[i]);                                     \
                float cg = sigm_f(a3[i]);                                     \
                float cn = __builtin_fmaf(fg, cadj, ig * cg);                 \
                float hn = og * tanh_f(cn);                                   \
                cst[i]  = cn;                                                 \
                hsum[i] += hn;                                                \
                sh_h[NXT][woff + i * LROW] = (_Float16)hn;                    \
                sh_c[NXT][woff + i * LROW] = (_Float16)cn;                    \
            }                                                                 \
        }                                                                     \
        /* rotate pipelines: NXT-parity raw regs hold step s+1 */             \
        xf0 = pack8(xi##NXT##_a, xi##NXT##_b);                                \
        xf1 = pack8(xi##NXT##_c, xi##NXT##_d);                                \
        dc0 = di##NXT##_0; dc1 = di##NXT##_1;                                 \
        dc2 = di##NXT##_2; dc3 = di##NXT##_3;                                 \
        __syncthreads();                                                      \
    }

    for (int s = 0; s < SS; s += 2) {
        TLSTM_STEP(s,     0, 1)
        TLSTM_STEP(s + 1, 1, 0)
    }
#undef TLSTM_STEP

    // ---- epilogue: out[b] = sum_u hsum[b][u]*W_out[u] + S*b_out ----
    #pragma unroll
    for (int i = 0; i < 4; ++i)
        sh_red[Q * 4 + i][unit] = hsum[i] * wout_r;
    __syncthreads();
    if (t < 128) {
        const int bb = t >> 3, seg = t & 7;
        float acc = 0.f;
        #pragma unroll
        for (int j = 0; j < 16; ++j) acc += sh_red[bb][seg * 16 + j];
        sh_r2[bb][seg] = acc;
    }
    __syncthreads();
    if (t < MB) {
        float acc = 0.f;
        #pragma unroll
        for (int j = 0; j < 8; ++j) acc += sh_r2[t][j];
        out[b0 + t] = acc + (float)SS * b_out[0];
    }
}

extern "C" void kernel_launch(void* const* d_in, const int* in_sizes, int n_in,
                              void* d_out, int out_size, void* d_ws, size_t ws_size,
                              hipStream_t stream) {
    const float* inputs        = (const float*)d_in[0];
    const float* time_interval = (const float*)d_in[1];
    const float* W_all         = (const float*)d_in[2];
    const float* b_all         = (const float*)d_in[3];
    const float* U_all         = (const float*)d_in[4];
    const float* b_u           = (const float*)d_in[5];
    const float* W_d           = (const float*)d_in[6];
    const float* b_d           = (const float*)d_in[7];
    const float* W_out         = (const float*)d_in[8];
    const float* b_out         = (const float*)d_in[9];
    float* out = (float*)d_out;

    tlstm_mfma2_kernel<<<dim3(NB), dim3(512), 0, stream>>>(
        inputs, time_interval, W_all, b_all, U_all, b_u,
        W_d, b_d, W_out, b_out, out);
}